// Round 4
// baseline (664.314 us; speedup 1.0000x reference)
//
#include <hip/hip_runtime.h>

typedef __attribute__((ext_vector_type(8))) short bf16x8;
typedef __attribute__((ext_vector_type(4))) float f32x4;

#define BB 1024
#define TT 256
#define DD 63
#define HH 128
#define CHUNK 2    // 2 batch rows per block -> 512 blocks -> 2 blocks/CU (independent barrier domains)
#define HSTR 160   // shorts; 80 dwords ≡ 16 (mod 32) -> A-frag reads exactly 2-way (free)
#define XSTR 96    // shorts; 48 dwords ≡ 16 (mod 32)

// Barrier that drains only LDS (lgkmcnt), NOT outstanding global loads.
#define LDS_BARRIER() asm volatile("s_waitcnt lgkmcnt(0)\n\ts_barrier" ::: "memory")

__device__ __forceinline__ short f2bf(float f) {
  unsigned u = __builtin_bit_cast(unsigned, f);
  u = (u + 0x7FFFu + ((u >> 16) & 1u)) >> 16;   // RNE
  return (short)u;
}
__device__ __forceinline__ float sigm(float x) {
  return __builtin_amdgcn_rcpf(1.f + __expf(-x));
}
__device__ __forceinline__ float tanh_fast(float x) {
  float e = __expf(2.f * x);
  return 1.f - 2.f * __builtin_amdgcn_rcpf(e + 1.f);
}

// 512 threads = 8 waves. Wave w: gate g=w>>1, column half w&1, 4 n-tiles each.
// B-frags register-resident (96 VGPR). 2 blocks/CU drift out of phase and hide
// each other's barrier/latency stalls (the R2/R3 lesson: waves inside ONE
// barrier schedule cannot do this).
__global__ __launch_bounds__(512, 4)
void lstm_fwd_kernel(const float* __restrict__ X,
                     const float* __restrict__ Wih,
                     const float* __restrict__ Whh,
                     const float* __restrict__ bih,
                     const float* __restrict__ bhh,
                     const float* __restrict__ Wfc,
                     float* __restrict__ out) {
  __shared__ __align__(16) short hbuf[4 * HSTR];          // h (bf16), rows 0..CHUNK-1 live, rest zero
  __shared__ __align__(16) short xbuf[2 * 4 * XSTR];      // x_t (bf16), 2 slots
  __shared__ __align__(16) float gl[512 * 4];             // gates, row-swizzled

  const int tid  = threadIdx.x;
  const int wave = tid >> 6;
  const int lane = tid & 63;
  const int quad = lane >> 4;
  const int l15  = lane & 15;
  const int b0   = blockIdx.x * CHUNK;
  const int g    = wave >> 1;
  const int half = wave & 1;
  const bool hib = (l15 >> 3) != 0;

  // ---- register-resident W fragments ----
  bf16x8 Bh[4][4];   // W_hh: tile, kstep(32)
  bf16x8 Bx[4][2];   // W_ih: tile, kstep(32), K padded 63->64
#pragma unroll
  for (int tile = 0; tile < 4; ++tile) {
    const int n = g * 128 + half * 64 + tile * 16 + l15;
    const float* wr = Whh + (size_t)n * HH;
#pragma unroll
    for (int ks = 0; ks < 4; ++ks) {
      const int k0 = ks * 32 + quad * 8;
      f32x4 w0 = *(const f32x4*)(wr + k0);
      f32x4 w1 = *(const f32x4*)(wr + k0 + 4);
      bf16x8 v;
#pragma unroll
      for (int jj = 0; jj < 4; ++jj) { v[jj] = f2bf(w0[jj]); v[4 + jj] = f2bf(w1[jj]); }
      Bh[tile][ks] = v;
    }
    const float* xr = Wih + (size_t)n * DD;
#pragma unroll
    for (int ks = 0; ks < 2; ++ks) {
      const int k0 = ks * 32 + quad * 8;
      bf16x8 v;
#pragma unroll
      for (int jj = 0; jj < 8; ++jj) {
        const int k = k0 + jj;
        v[jj] = (k < DD) ? f2bf(xr[k]) : (short)0;
      }
      Bx[tile][ks] = v;
    }
  }

  // elementwise mapping: col j, row r (only r < CHUNK is live)
  const int j = tid & 127;
  const int r = tid >> 7;
  const int s = (r + (j >> 3)) & 3;   // swizzle slot for gate reads
  const bool rlive = (r < CHUNK);
  float bg[4];
#pragma unroll
  for (int gg = 0; gg < 4; ++gg) bg[gg] = bih[gg * HH + j] + bhh[gg * HH + j];

  for (int i = tid; i < 4 * HSTR; i += 512) hbuf[i] = 0;

  // x prefetch: CHUNK rows x 63 cols threads; distance-2 pipeline
  const int xrow = tid / DD;
  const int xd   = tid - xrow * DD;
  const bool xthr = (tid < CHUNK * DD);
  const float* xptr = X + ((size_t)(b0 + xrow) * TT) * DD + xd;
  float xv_pend = 0.f;
  if (xthr) {
    xbuf[xrow * XSTR + xd] = f2bf(xptr[0]);   // slot 0 = x(0)
    xv_pend = xptr[DD];                        // x(1)
    xptr += 2 * DD;
  } else if (tid < 4 * DD) {
    // zero the dead x rows once so garbage D-rows stay finite
    xbuf[xrow * XSTR + xd] = 0;
    xbuf[4 * XSTR + xrow * XSTR + xd] = 0;
  }
  __syncthreads();

  float cc = 0.f, hv = 0.f;
  const f32x4 zero4 = {0.f, 0.f, 0.f, 0.f};

  for (int t = 0; t < TT; ++t) {
    const int cur = (t & 1) * (4 * XSTR);

    // issue next-next x load early (stays in flight across lgkm-only barriers)
    float xv_new = 0.f;
    const bool pf2 = xthr && (t + 2 < TT);
    if (pf2) { xv_new = *xptr; xptr += DD; }

    // A-fragments: rows via l15&3 -> broadcast
    bf16x8 Ah[4], Ax[2];
#pragma unroll
    for (int ks = 0; ks < 4; ++ks)
      Ah[ks] = *(const bf16x8*)&hbuf[(l15 & 3) * HSTR + ks * 32 + quad * 8];
#pragma unroll
    for (int ks = 0; ks < 2; ++ks)
      Ax[ks] = *(const bf16x8*)&xbuf[cur + (l15 & 3) * XSTR + ks * 32 + quad * 8];

    // ---- MFMA: gates = h @ Whh^T + x @ Wih^T ----
    f32x4 acc[4];
#pragma unroll
    for (int tile = 0; tile < 4; ++tile)
      acc[tile] = __builtin_amdgcn_mfma_f32_16x16x32_bf16(Ah[0], Bh[tile][0], zero4, 0, 0, 0);
#pragma unroll
    for (int ks = 1; ks < 4; ++ks)
#pragma unroll
      for (int tile = 0; tile < 4; ++tile)
        acc[tile] = __builtin_amdgcn_mfma_f32_16x16x32_bf16(Ah[ks], Bh[tile][ks], acc[tile], 0, 0, 0);
#pragma unroll
    for (int ks = 0; ks < 2; ++ks)
#pragma unroll
      for (int tile = 0; tile < 4; ++tile)
        acc[tile] = __builtin_amdgcn_mfma_f32_16x16x32_bf16(Ax[ks], Bx[tile][ks], acc[tile], 0, 0, 0);

    // ---- gate write: b128 at n*4 with rows rotated by (n>>3)&3 ----
    if (quad == 0) {
#pragma unroll
      for (int tile = 0; tile < 4; ++tile) {
        const int n = g * 128 + half * 64 + tile * 16 + l15;
        const int rb = (tile * 2) & 3;          // static part of rot
        f32x4 a = acc[tile];
        f32x4 ts;
        ts[0] = a[(4 - rb) & 3];
        ts[1] = a[(5 - rb) & 3];
        ts[2] = a[(6 - rb) & 3];
        ts[3] = a[(7 - rb) & 3];
        f32x4 o;                                 // dynamic rotate by hib
        o[0] = hib ? ts[3] : ts[0];
        o[1] = hib ? ts[0] : ts[1];
        o[2] = hib ? ts[1] : ts[2];
        o[3] = hib ? ts[2] : ts[3];
        *(f32x4*)&gl[(size_t)n * 4] = o;
      }
    }
    LDS_BARRIER();

    // ---- elementwise: 1 element per thread (r<CHUNK live) ----
    const float vi = gl[0 * 512 + 4 * j + s];
    const float vf = gl[1 * 512 + 4 * j + s];
    const float vg = gl[2 * 512 + 4 * j + s];
    const float vo = gl[3 * 512 + 4 * j + s];
    {
      const float iv = sigm(vi + bg[0]);
      const float fv = sigm(vf + bg[1]);
      const float gv = tanh_fast(vg + bg[2]);
      const float ov = sigm(vo + bg[3]);
      cc = fv * cc + iv * gv;
      hv = ov * tanh_fast(cc);
      if (rlive) hbuf[r * HSTR + j] = f2bf(hv);
    }

    if (xthr && (t + 1 < TT))
      xbuf[(cur ^ (4 * XSTR)) + xrow * XSTR + xd] = f2bf(xv_pend);
    xv_pend = xv_new;
    LDS_BARRIER();
  }

  // ---- epilogue: forward half of FC (fp32, no bias) ----
  if (rlive) gl[r * HH + j] = hv;   // stage h_f(T-1) as fp32 [CHUNK][128]
  __syncthreads();
  if (tid < CHUNK * 14) {
    const int rr = tid / 14, o = tid - rr * 14;
    const float* wr = Wfc + (size_t)o * (2 * HH);
    float acc = 0.f;
#pragma unroll 16
    for (int k = 0; k < HH; ++k) acc += wr[k] * gl[rr * HH + k];
    out[(size_t)(b0 + rr) * 14 + o] = acc;
  }
}

// Backward direction collapses to ONE cell step on x[:,T-1] (h0=c0=0),
// done in exact fp32, plus the backward half of the FC (+ biases).
__global__ __launch_bounds__(256, 2)
void lstm_bwd_fc_kernel(const float* __restrict__ X,
                        const float* __restrict__ Wih_b,
                        const float* __restrict__ bih_b,
                        const float* __restrict__ bhh_b,
                        const float* __restrict__ Wfc,
                        const float* __restrict__ bfc,
                        float* __restrict__ out) {
  __shared__ float xl[DD];
  __shared__ float glb[4 * HH];
  __shared__ float hl[HH];
  __shared__ float pl[14 * 8];
  const int b = blockIdx.x;
  const int tid = threadIdx.x;

  if (tid < DD) xl[tid] = X[((size_t)b * TT + (TT - 1)) * DD + tid];
  __syncthreads();

#pragma unroll
  for (int u = 0; u < 2; ++u) {
    const int n = tid * 2 + u;
    const float* wr = Wih_b + (size_t)n * DD;
    float acc = bih_b[n] + bhh_b[n];
#pragma unroll
    for (int k = 0; k < DD; ++k) acc += wr[k] * xl[k];
    glb[n] = acc;
  }
  __syncthreads();

  if (tid < HH) {
    float iv = sigm(glb[0 * HH + tid]);
    float gv = tanh_fast(glb[2 * HH + tid]);
    float ov = sigm(glb[3 * HH + tid]);
    hl[tid] = ov * tanh_fast(iv * gv);   // c = f*0 + i*g
  }
  __syncthreads();

  if (tid < 14 * 8) {
    const int o = tid >> 3, kp = tid & 7;
    const float* wr = Wfc + (size_t)o * (2 * HH) + HH;
    float acc = 0.f;
#pragma unroll
    for (int i = 0; i < 16; ++i) {
      const int jj = kp * 16 + i;
      acc += wr[jj] * hl[jj];
    }
    pl[tid] = acc;
  }
  __syncthreads();

  if (tid < 14) {
    float acc = bfc[tid];
#pragma unroll
    for (int i = 0; i < 8; ++i) acc += pl[tid * 8 + i];
    out[(size_t)b * 14 + tid] += acc;   // add to forward partial
  }
}

extern "C" void kernel_launch(void* const* d_in, const int* in_sizes, int n_in,
                              void* d_out, int out_size, void* d_ws, size_t ws_size,
                              hipStream_t stream) {
  const float* X     = (const float*)d_in[0];
  const float* Wih_f = (const float*)d_in[1];
  const float* Whh_f = (const float*)d_in[2];
  const float* bih_f = (const float*)d_in[3];
  const float* bhh_f = (const float*)d_in[4];
  const float* Wih_b = (const float*)d_in[5];
  // d_in[6] = W_hh_b: unused (backward dir needs only one step from zero state)
  const float* bih_b = (const float*)d_in[7];
  const float* bhh_b = (const float*)d_in[8];
  const float* Wfc   = (const float*)d_in[9];
  const float* bfc   = (const float*)d_in[10];
  float* out = (float*)d_out;

  lstm_fwd_kernel<<<BB / CHUNK, 512, 0, stream>>>(X, Wih_f, Whh_f, bih_f, bhh_f, Wfc, out);
  lstm_bwd_fc_kernel<<<BB, 256, 0, stream>>>(X, Wih_b, bih_b, bhh_b, Wfc, bfc, out);
}

// Round 5
// 629.666 us; speedup vs baseline: 1.0550x; 1.0550x over previous
//
#include <hip/hip_runtime.h>

typedef __attribute__((ext_vector_type(8))) short bf16x8;
typedef __attribute__((ext_vector_type(4))) float f32x4;

#define BB 1024
#define TT 256
#define DD 63
#define HH 128
#define CHUNK 2    // 2 batch rows/block -> grid 512 -> 2 blocks/CU (independent barrier domains)
#define HSTR 160   // shorts; 80 dwords ≡ 16 (mod 32) -> A-frag reads 2-way (free)
#define XSTR 96    // shorts; 48 dwords ≡ 16 (mod 32)

// Barrier that drains only LDS (lgkmcnt), NOT outstanding global loads.
#define LDS_BARRIER() asm volatile("s_waitcnt lgkmcnt(0)\n\ts_barrier" ::: "memory")

__device__ __forceinline__ short f2bf(float f) {
  unsigned u = __builtin_bit_cast(unsigned, f);
  u = (u + 0x7FFFu + ((u >> 16) & 1u)) >> 16;   // RNE
  return (short)u;
}
__device__ __forceinline__ float sigm(float x) {
  return __builtin_amdgcn_rcpf(1.f + __expf(-x));
}
__device__ __forceinline__ float tanh_fast(float x) {
  float e = __expf(2.f * x);
  return 1.f - 2.f * __builtin_amdgcn_rcpf(e + 1.f);
}

// 512 threads = 8 waves. Wave w: gate g=w>>1, column half w&1, 4 n-tiles each.
// B-frags register-resident (96 VGPR -> kernel 112 VGPR total).
// CRITICAL: launch_bounds min-waves stays 2 — R4's (512,4) clamped VGPR to 64
// and spilled the weights to scratch (177 MB WRITE_SIZE, 2.4x regression).
// 2 blocks/CU co-residency comes from VGPR=112<=128, not from the bound.
__global__ __launch_bounds__(512, 2)
void lstm_fwd_kernel(const float* __restrict__ X,
                     const float* __restrict__ Wih,
                     const float* __restrict__ Whh,
                     const float* __restrict__ bih,
                     const float* __restrict__ bhh,
                     const float* __restrict__ Wfc,
                     float* __restrict__ out) {
  __shared__ __align__(16) short hbuf[4 * HSTR];          // h (bf16), rows 0..CHUNK-1 live, rest zero
  __shared__ __align__(16) short xbuf[2 * 4 * XSTR];      // x_t (bf16), 2 slots
  __shared__ __align__(16) float gl[512 * 4];             // gates, row-swizzled

  const int tid  = threadIdx.x;
  const int wave = tid >> 6;
  const int lane = tid & 63;
  const int quad = lane >> 4;
  const int l15  = lane & 15;
  const int b0   = blockIdx.x * CHUNK;
  const int g    = wave >> 1;
  const int half = wave & 1;
  const bool hib = (l15 >> 3) != 0;

  // ---- register-resident W fragments ----
  bf16x8 Bh[4][4];   // W_hh: tile, kstep(32)
  bf16x8 Bx[4][2];   // W_ih: tile, kstep(32), K padded 63->64
#pragma unroll
  for (int tile = 0; tile < 4; ++tile) {
    const int n = g * 128 + half * 64 + tile * 16 + l15;
    const float* wr = Whh + (size_t)n * HH;
#pragma unroll
    for (int ks = 0; ks < 4; ++ks) {
      const int k0 = ks * 32 + quad * 8;
      f32x4 w0 = *(const f32x4*)(wr + k0);
      f32x4 w1 = *(const f32x4*)(wr + k0 + 4);
      bf16x8 v;
#pragma unroll
      for (int jj = 0; jj < 4; ++jj) { v[jj] = f2bf(w0[jj]); v[4 + jj] = f2bf(w1[jj]); }
      Bh[tile][ks] = v;
    }
    const float* xr = Wih + (size_t)n * DD;
#pragma unroll
    for (int ks = 0; ks < 2; ++ks) {
      const int k0 = ks * 32 + quad * 8;
      bf16x8 v;
#pragma unroll
      for (int jj = 0; jj < 8; ++jj) {
        const int k = k0 + jj;
        v[jj] = (k < DD) ? f2bf(xr[k]) : (short)0;
      }
      Bx[tile][ks] = v;
    }
  }

  // elementwise mapping: col j, row r (only r < CHUNK is live)
  const int j = tid & 127;
  const int r = tid >> 7;
  const int s = (r + (j >> 3)) & 3;   // swizzle slot for gate reads
  const bool rlive = (r < CHUNK);
  float bg[4];
#pragma unroll
  for (int gg = 0; gg < 4; ++gg) bg[gg] = bih[gg * HH + j] + bhh[gg * HH + j];

  for (int i = tid; i < 4 * HSTR; i += 512) hbuf[i] = 0;

  // x prefetch: CHUNK rows x 63 cols threads; distance-2 pipeline
  const int xrow = tid / DD;
  const int xd   = tid - xrow * DD;
  const bool xthr = (tid < CHUNK * DD);
  const float* xptr = X + ((size_t)(b0 + xrow) * TT) * DD + xd;
  float xv_pend = 0.f;
  if (xthr) {
    xbuf[xrow * XSTR + xd] = f2bf(xptr[0]);   // slot 0 = x(0)
    xv_pend = xptr[DD];                        // x(1)
    xptr += 2 * DD;
  } else if (tid < 4 * DD) {
    // zero the dead x rows once so garbage D-rows stay finite
    xbuf[xrow * XSTR + xd] = 0;
    xbuf[4 * XSTR + xrow * XSTR + xd] = 0;
  }
  __syncthreads();

  float cc = 0.f, hv = 0.f;
  const f32x4 zero4 = {0.f, 0.f, 0.f, 0.f};

  for (int t = 0; t < TT; ++t) {
    const int cur = (t & 1) * (4 * XSTR);

    // issue next-next x load early (stays in flight across lgkm-only barriers)
    float xv_new = 0.f;
    const bool pf2 = xthr && (t + 2 < TT);
    if (pf2) { xv_new = *xptr; xptr += DD; }

    // A-fragments: rows via l15&3 -> same-address broadcast within quads
    bf16x8 Ah[4], Ax[2];
#pragma unroll
    for (int ks = 0; ks < 4; ++ks)
      Ah[ks] = *(const bf16x8*)&hbuf[(l15 & 3) * HSTR + ks * 32 + quad * 8];
#pragma unroll
    for (int ks = 0; ks < 2; ++ks)
      Ax[ks] = *(const bf16x8*)&xbuf[cur + (l15 & 3) * XSTR + ks * 32 + quad * 8];

    // ---- MFMA: gates = h @ Whh^T + x @ Wih^T ----
    f32x4 acc[4];
#pragma unroll
    for (int tile = 0; tile < 4; ++tile)
      acc[tile] = __builtin_amdgcn_mfma_f32_16x16x32_bf16(Ah[0], Bh[tile][0], zero4, 0, 0, 0);
#pragma unroll
    for (int ks = 1; ks < 4; ++ks)
#pragma unroll
      for (int tile = 0; tile < 4; ++tile)
        acc[tile] = __builtin_amdgcn_mfma_f32_16x16x32_bf16(Ah[ks], Bh[tile][ks], acc[tile], 0, 0, 0);
#pragma unroll
    for (int ks = 0; ks < 2; ++ks)
#pragma unroll
      for (int tile = 0; tile < 4; ++tile)
        acc[tile] = __builtin_amdgcn_mfma_f32_16x16x32_bf16(Ax[ks], Bx[tile][ks], acc[tile], 0, 0, 0);

    // ---- gate write: b128 at n*4 with rows rotated by (n>>3)&3 ----
    if (quad == 0) {
#pragma unroll
      for (int tile = 0; tile < 4; ++tile) {
        const int n = g * 128 + half * 64 + tile * 16 + l15;
        const int rb = (tile * 2) & 3;          // static part of rot
        f32x4 a = acc[tile];
        f32x4 ts;
        ts[0] = a[(4 - rb) & 3];
        ts[1] = a[(5 - rb) & 3];
        ts[2] = a[(6 - rb) & 3];
        ts[3] = a[(7 - rb) & 3];
        f32x4 o;                                 // dynamic rotate by hib
        o[0] = hib ? ts[3] : ts[0];
        o[1] = hib ? ts[0] : ts[1];
        o[2] = hib ? ts[1] : ts[2];
        o[3] = hib ? ts[2] : ts[3];
        *(f32x4*)&gl[(size_t)n * 4] = o;
      }
    }
    LDS_BARRIER();

    // ---- elementwise: 1 element per thread (r<CHUNK live) ----
    const float vi = gl[0 * 512 + 4 * j + s];
    const float vf = gl[1 * 512 + 4 * j + s];
    const float vg = gl[2 * 512 + 4 * j + s];
    const float vo = gl[3 * 512 + 4 * j + s];
    {
      const float iv = sigm(vi + bg[0]);
      const float fv = sigm(vf + bg[1]);
      const float gv = tanh_fast(vg + bg[2]);
      const float ov = sigm(vo + bg[3]);
      cc = fv * cc + iv * gv;
      hv = ov * tanh_fast(cc);
      if (rlive) hbuf[r * HSTR + j] = f2bf(hv);
    }

    if (xthr && (t + 1 < TT))
      xbuf[(cur ^ (4 * XSTR)) + xrow * XSTR + xd] = f2bf(xv_pend);
    xv_pend = xv_new;
    LDS_BARRIER();
  }

  // ---- epilogue: forward half of FC (fp32, no bias) ----
  if (rlive) gl[r * HH + j] = hv;   // stage h_f(T-1) as fp32 [CHUNK][128]
  __syncthreads();
  if (tid < CHUNK * 14) {
    const int rr = tid / 14, o = tid - rr * 14;
    const float* wr = Wfc + (size_t)o * (2 * HH);
    float acc = 0.f;
#pragma unroll 16
    for (int k = 0; k < HH; ++k) acc += wr[k] * gl[rr * HH + k];
    out[(size_t)(b0 + rr) * 14 + o] = acc;
  }
}

// Backward direction collapses to ONE cell step on x[:,T-1] (h0=c0=0),
// done in exact fp32, plus the backward half of the FC (+ biases).
__global__ __launch_bounds__(256, 2)
void lstm_bwd_fc_kernel(const float* __restrict__ X,
                        const float* __restrict__ Wih_b,
                        const float* __restrict__ bih_b,
                        const float* __restrict__ bhh_b,
                        const float* __restrict__ Wfc,
                        const float* __restrict__ bfc,
                        float* __restrict__ out) {
  __shared__ float xl[DD];
  __shared__ float glb[4 * HH];
  __shared__ float hl[HH];
  __shared__ float pl[14 * 8];
  const int b = blockIdx.x;
  const int tid = threadIdx.x;

  if (tid < DD) xl[tid] = X[((size_t)b * TT + (TT - 1)) * DD + tid];
  __syncthreads();

#pragma unroll
  for (int u = 0; u < 2; ++u) {
    const int n = tid * 2 + u;
    const float* wr = Wih_b + (size_t)n * DD;
    float acc = bih_b[n] + bhh_b[n];
#pragma unroll
    for (int k = 0; k < DD; ++k) acc += wr[k] * xl[k];
    glb[n] = acc;
  }
  __syncthreads();

  if (tid < HH) {
    float iv = sigm(glb[0 * HH + tid]);
    float gv = tanh_fast(glb[2 * HH + tid]);
    float ov = sigm(glb[3 * HH + tid]);
    hl[tid] = ov * tanh_fast(iv * gv);   // c = f*0 + i*g
  }
  __syncthreads();

  if (tid < 14 * 8) {
    const int o = tid >> 3, kp = tid & 7;
    const float* wr = Wfc + (size_t)o * (2 * HH) + HH;
    float acc = 0.f;
#pragma unroll
    for (int i = 0; i < 16; ++i) {
      const int jj = kp * 16 + i;
      acc += wr[jj] * hl[jj];
    }
    pl[tid] = acc;
  }
  __syncthreads();

  if (tid < 14) {
    float acc = bfc[tid];
#pragma unroll
    for (int i = 0; i < 8; ++i) acc += pl[tid * 8 + i];
    out[(size_t)b * 14 + tid] += acc;   // add to forward partial
  }
}

extern "C" void kernel_launch(void* const* d_in, const int* in_sizes, int n_in,
                              void* d_out, int out_size, void* d_ws, size_t ws_size,
                              hipStream_t stream) {
  const float* X     = (const float*)d_in[0];
  const float* Wih_f = (const float*)d_in[1];
  const float* Whh_f = (const float*)d_in[2];
  const float* bih_f = (const float*)d_in[3];
  const float* bhh_f = (const float*)d_in[4];
  const float* Wih_b = (const float*)d_in[5];
  // d_in[6] = W_hh_b: unused (backward dir needs only one step from zero state)
  const float* bih_b = (const float*)d_in[7];
  const float* bhh_b = (const float*)d_in[8];
  const float* Wfc   = (const float*)d_in[9];
  const float* bfc   = (const float*)d_in[10];
  float* out = (float*)d_out;

  lstm_fwd_kernel<<<BB / CHUNK, 512, 0, stream>>>(X, Wih_f, Whh_f, bih_f, bhh_f, Wfc, out);
  lstm_bwd_fc_kernel<<<BB, 256, 0, stream>>>(X, Wih_b, bih_b, bhh_b, Wfc, bfc, out);
}

// Round 6
// 356.783 us; speedup vs baseline: 1.8620x; 1.7648x over previous
//
#include <hip/hip_runtime.h>

typedef __attribute__((ext_vector_type(8))) short bf16x8;
typedef __attribute__((ext_vector_type(4))) float f32x4;

#define BB 1024
#define TT 256
#define DD 63
#define HH 128
#define CHUNK 4    // 4 batch rows/block, grid 256 = 1 block/CU
#define HSTR 160   // shorts; 80 dwords ≡ 16 (mod 32) -> A-frag reads 2-way (free)
#define XSTR 96    // shorts; 48 dwords ≡ 16 (mod 32)

// Barrier that drains only LDS (lgkmcnt), NOT outstanding global loads.
// __syncthreads() emits s_waitcnt vmcnt(0) and would kill the x prefetch.
#define LDS_BARRIER() asm volatile("s_waitcnt lgkmcnt(0)\n\ts_barrier" ::: "memory")

__device__ __forceinline__ short f2bf(float f) {
  unsigned u = __builtin_bit_cast(unsigned, f);
  u = (u + 0x7FFFu + ((u >> 16) & 1u)) >> 16;   // RNE
  return (short)u;
}
__device__ __forceinline__ float sigm(float x) {
  return __builtin_amdgcn_rcpf(1.f + __expf(-x));
}
__device__ __forceinline__ float tanh_fast(float x) {
  float e = __expf(2.f * x);
  return 1.f - 2.f * __builtin_amdgcn_rcpf(e + 1.f);
}

// R6 structure: wave w owns cols [w*16, w*16+16) for ALL FOUR gates
// (B-frags: 4 gates x 6 ksteps x 4 VGPR = 96, same budget as R3).
// -> gate redistribution is IN-WAVE via private LDS scratch (no barrier),
// -> elementwise uses all 64 lanes (1 elem each, no exec masks),
// -> bias folded into MFMA C operand,
// -> h double-buffered  => ONE lgkm-only barrier per timestep
//    (R3/R5's 2-barrier, 3-LDS-round-trip chain measured ~2590 cyc/step).
// Lessons kept: launch_bounds 2nd arg=2 (R4's 4 clamped VGPR->64, spilled
// weights, 177MB scratch traffic); 2-blocks/CU co-residency does not happen
// under this bound (R5: serial rounds), so grid=256 = exactly 1 block/CU.
__global__ __launch_bounds__(512, 2)
void lstm_fwd_kernel(const float* __restrict__ X,
                     const float* __restrict__ Wih,
                     const float* __restrict__ Whh,
                     const float* __restrict__ bih,
                     const float* __restrict__ bhh,
                     const float* __restrict__ Wfc,
                     float* __restrict__ out) {
  __shared__ __align__(16) short hbuf[2 * 4 * HSTR];   // h (bf16), double-buffered, rows 0..3
  __shared__ __align__(16) short xbuf[2 * 4 * XSTR];   // x_t (bf16), 2 slots
  __shared__ __align__(16) float gsc[8 * 256];         // per-wave gate scratch (4g x 16col x 4row)

  const int tid  = threadIdx.x;
  const int wave = tid >> 6;
  const int lane = tid & 63;
  const int quad = lane >> 4;
  const int l15  = lane & 15;
  const int b0   = blockIdx.x * CHUNK;

  // ---- register-resident W fragments: all 4 gates, 16 cols per wave ----
  bf16x8 Bh[4][4];   // [gate][kstep], W_hh
  bf16x8 Bx[4][2];   // [gate][kstep], W_ih (K padded 63->64)
  f32x4  bias[4];    // gate bias replicated across the 4 acc rows (MFMA C init)
#pragma unroll
  for (int g = 0; g < 4; ++g) {
    const int n = g * 128 + wave * 16 + l15;
    const float* wr = Whh + (size_t)n * HH;
#pragma unroll
    for (int ks = 0; ks < 4; ++ks) {
      const int k0 = ks * 32 + quad * 8;
      f32x4 w0 = *(const f32x4*)(wr + k0);
      f32x4 w1 = *(const f32x4*)(wr + k0 + 4);
      bf16x8 v;
#pragma unroll
      for (int jj = 0; jj < 4; ++jj) { v[jj] = f2bf(w0[jj]); v[4 + jj] = f2bf(w1[jj]); }
      Bh[g][ks] = v;
    }
    const float* xr = Wih + (size_t)n * DD;
#pragma unroll
    for (int ks = 0; ks < 2; ++ks) {
      const int k0 = ks * 32 + quad * 8;
      bf16x8 v;
#pragma unroll
      for (int jj = 0; jj < 8; ++jj) {
        const int k = k0 + jj;
        v[jj] = (k < DD) ? f2bf(xr[k]) : (short)0;
      }
      Bx[g][ks] = v;
    }
    const float bv = bih[n] + bhh[n];
    bias[g] = (f32x4){bv, bv, bv, bv};
  }

  // zero h slot 0 (h(0) = 0); slot 1 is fully written at t=0
  for (int i = tid; i < 4 * HSTR; i += 512) hbuf[i] = 0;

  // x prefetch: 4 rows x 63 cols = 252 threads; distance-2 pipeline
  const int xrow = tid / DD;
  const int xd   = tid - xrow * DD;
  const bool xthr = (tid < CHUNK * DD);
  const float* xptr = X + ((size_t)(b0 + xrow) * TT) * DD + xd;
  float xv_pend = 0.f;
  if (xthr) {
    xbuf[xrow * XSTR + xd] = f2bf(xptr[0]);   // slot 0 = x(0)
    xv_pend = xptr[DD];                        // x(1)
    xptr += 2 * DD;
  }
  __syncthreads();

  const int wbase = wave * 256;                // private gsc region
  const int gidx  = wbase + l15 * 4 + quad;    // this lane's (col,row) gate slot
  float cc = 0.f, hv = 0.f;

  for (int t = 0; t < TT; ++t) {
    const int xcur = (t & 1) * (4 * XSTR);
    const int hcur = (t & 1) * (4 * HSTR);

    // issue x(t+2) load early; stays in flight across the lgkm-only barrier
    float xv_new = 0.f;
    const bool pf2 = xthr && (t + 2 < TT);
    if (pf2) { xv_new = *xptr; xptr += DD; }

    // A-fragments (rows via l15&3 -> same-address broadcast within quads)
    bf16x8 Ah[4], Ax[2];
#pragma unroll
    for (int ks = 0; ks < 4; ++ks)
      Ah[ks] = *(const bf16x8*)&hbuf[hcur + (l15 & 3) * HSTR + ks * 32 + quad * 8];
#pragma unroll
    for (int ks = 0; ks < 2; ++ks)
      Ax[ks] = *(const bf16x8*)&xbuf[xcur + (l15 & 3) * XSTR + ks * 32 + quad * 8];

    // ---- MFMA: acc[g] = bias[g] + h @ Whh^T + x @ Wih^T (4 indep chains) ----
    f32x4 acc[4];
#pragma unroll
    for (int g = 0; g < 4; ++g)
      acc[g] = __builtin_amdgcn_mfma_f32_16x16x32_bf16(Ah[0], Bh[g][0], bias[g], 0, 0, 0);
#pragma unroll
    for (int ks = 1; ks < 4; ++ks)
#pragma unroll
      for (int g = 0; g < 4; ++g)
        acc[g] = __builtin_amdgcn_mfma_f32_16x16x32_bf16(Ah[ks], Bh[g][ks], acc[g], 0, 0, 0);
#pragma unroll
    for (int ks = 0; ks < 2; ++ks)
#pragma unroll
      for (int g = 0; g < 4; ++g)
        acc[g] = __builtin_amdgcn_mfma_f32_16x16x32_bf16(Ax[ks], Bx[g][ks], acc[g], 0, 0, 0);

    // ---- in-wave gate redistribute (private region: NO barrier needed) ----
    // quad0 lane l15 holds rows 0-3 of col l15 in regs 0-3; write b128,
    // then every lane reads its (row=quad, col=l15) scalar per gate.
    if (quad == 0) {
#pragma unroll
      for (int g = 0; g < 4; ++g)
        *(f32x4*)&gsc[wbase + g * 64 + l15 * 4] = acc[g];
    }
    const float gi_ = gsc[gidx];          // compiler inserts lgkmcnt between
    const float gf_ = gsc[gidx + 64];     // the write above and these reads
    const float gg_ = gsc[gidx + 128];
    const float go_ = gsc[gidx + 192];

    // ---- elementwise: all 64 lanes, 1 element each ----
    const float iv = sigm(gi_);
    const float fv = sigm(gf_);
    const float gv = tanh_fast(gg_);
    const float ov = sigm(go_);
    cc = fv * cc + iv * gv;
    hv = ov * tanh_fast(cc);
    hbuf[(hcur ^ (4 * HSTR)) + quad * HSTR + wave * 16 + l15] = f2bf(hv);

    if (xthr && (t + 1 < TT))
      xbuf[(xcur ^ (4 * XSTR)) + xrow * XSTR + xd] = f2bf(xv_pend);
    xv_pend = xv_new;
    LDS_BARRIER();   // the ONE barrier: h/x produced -> consumed next step
  }

  // ---- epilogue: forward half of FC (fp32, no bias) ----
  // reuse gsc (safe: final LDS_BARRIER above) as h_f staging [4][128] fp32
  gsc[quad * HH + wave * 16 + l15] = hv;
  __syncthreads();
  if (tid < CHUNK * 14) {
    const int rr = tid / 14, o = tid - rr * 14;
    const float* wr = Wfc + (size_t)o * (2 * HH);
    float acc = 0.f;
#pragma unroll 16
    for (int k = 0; k < HH; ++k) acc += wr[k] * gsc[rr * HH + k];
    out[(size_t)(b0 + rr) * 14 + o] = acc;
  }
}

// Backward direction collapses to ONE cell step on x[:,T-1] (h0=c0=0),
// done in exact fp32, plus the backward half of the FC (+ biases).
__global__ __launch_bounds__(256, 2)
void lstm_bwd_fc_kernel(const float* __restrict__ X,
                        const float* __restrict__ Wih_b,
                        const float* __restrict__ bih_b,
                        const float* __restrict__ bhh_b,
                        const float* __restrict__ Wfc,
                        const float* __restrict__ bfc,
                        float* __restrict__ out) {
  __shared__ float xl[DD];
  __shared__ float glb[4 * HH];
  __shared__ float hl[HH];
  __shared__ float pl[14 * 8];
  const int b = blockIdx.x;
  const int tid = threadIdx.x;

  if (tid < DD) xl[tid] = X[((size_t)b * TT + (TT - 1)) * DD + tid];
  __syncthreads();

#pragma unroll
  for (int u = 0; u < 2; ++u) {
    const int n = tid * 2 + u;
    const float* wr = Wih_b + (size_t)n * DD;
    float acc = bih_b[n] + bhh_b[n];
#pragma unroll
    for (int k = 0; k < DD; ++k) acc += wr[k] * xl[k];
    glb[n] = acc;
  }
  __syncthreads();

  if (tid < HH) {
    float iv = sigm(glb[0 * HH + tid]);
    float gv = tanh_fast(glb[2 * HH + tid]);
    float ov = sigm(glb[3 * HH + tid]);
    hl[tid] = ov * tanh_fast(iv * gv);   // c = f*0 + i*g
  }
  __syncthreads();

  if (tid < 14 * 8) {
    const int o = tid >> 3, kp = tid & 7;
    const float* wr = Wfc + (size_t)o * (2 * HH) + HH;
    float acc = 0.f;
#pragma unroll
    for (int i = 0; i < 16; ++i) {
      const int jj = kp * 16 + i;
      acc += wr[jj] * hl[jj];
    }
    pl[tid] = acc;
  }
  __syncthreads();

  if (tid < 14) {
    float acc = bfc[tid];
#pragma unroll
    for (int i = 0; i < 8; ++i) acc += pl[tid * 8 + i];
    out[(size_t)b * 14 + tid] += acc;   // add to forward partial
  }
}

extern "C" void kernel_launch(void* const* d_in, const int* in_sizes, int n_in,
                              void* d_out, int out_size, void* d_ws, size_t ws_size,
                              hipStream_t stream) {
  const float* X     = (const float*)d_in[0];
  const float* Wih_f = (const float*)d_in[1];
  const float* Whh_f = (const float*)d_in[2];
  const float* bih_f = (const float*)d_in[3];
  const float* bhh_f = (const float*)d_in[4];
  const float* Wih_b = (const float*)d_in[5];
  // d_in[6] = W_hh_b: unused (backward dir needs only one step from zero state)
  const float* bih_b = (const float*)d_in[7];
  const float* bhh_b = (const float*)d_in[8];
  const float* Wfc   = (const float*)d_in[9];
  const float* bfc   = (const float*)d_in[10];
  float* out = (float*)d_out;

  lstm_fwd_kernel<<<BB / CHUNK, 512, 0, stream>>>(X, Wih_f, Whh_f, bih_f, bhh_f, Wfc, out);
  lstm_bwd_fc_kernel<<<BB, 256, 0, stream>>>(X, Wih_b, bih_b, bhh_b, Wfc, bfc, out);
}